// Round 6
// baseline (179.449 us; speedup 1.0000x reference)
//
#include <hip/hip_runtime.h>

// R10 = R9 + LDS zero-init fix. R9's removal of x-staging left act cols 16..31
// uninitialized (read by layer-1/2 stage_a against zero-padded weights); garbage
// NaN * 0 = NaN through MFMA. Zero the wave's 8KB buffer first (8 b128/lane).
// Structure: 16 waves/block (1024 thr), one wave-private barrier-free gauss
// chain per sample, 16 samples in 128KB LDS -> 4 latency streams/SIMD.
// - layer-0 A-frags direct from global fp32 x (no LDS x round-trip).
// - sched_barrier(0x7F) fences DS ops only; VALU/MFMA/VMEM pipeline across.
// - dense0: 16-sample A-tile, 16-way K split, 16-wave reduce.

typedef _Float16 f16x8 __attribute__((ext_vector_type(8)));
typedef _Float16 f16x4 __attribute__((ext_vector_type(4)));
typedef float    f32x4 __attribute__((ext_vector_type(4)));

// ws layout (halves): [0] wm0 tiled [128][80][32]; K~ [4][64][64]; padded weights
#define KT_OFF    327680
#define W0P_OFF   344064               // [16][64], rows>=8 zero
#define W1P_OFF   345088               // [16][32], cols>=8 zero
#define W2P_OFF   345600               // [32][32], cols>=16 zero
#define W3P_OFF   346624               // [64][32]

__global__ void prep_all(const float* __restrict__ s0, const float* __restrict__ s1,
                         const float* __restrict__ s2, const float* __restrict__ s3,
                         const float* __restrict__ w0, const float* __restrict__ w1,
                         const float* __restrict__ w2, const float* __restrict__ w3,
                         const float* __restrict__ wm0, _Float16* __restrict__ base) {
  int bid = blockIdx.x, tid = threadIdx.x;
  if (bid < 1280) {
    // wm0 fp32 [80][4096] -> fp16 tiled [kc][n][32]
    int idx = bid * 256 + tid;
    int kc = idx / 2560, rem = idx % 2560;
    int n = rem >> 5, o = rem & 31;
    base[idx] = (_Float16)wm0[n * 4096 + kc * 32 + o];
  } else if (bid == 1280) {
    // K~ : L1-normalized gaussian rows, fp16 [4][64][64]
    int li = tid >> 6, i = tid & 63;
    float sg = (li == 0) ? s0[0] : (li == 1) ? s1[0] : (li == 2) ? s2[0] : s3[0];
    float denom = 2.0f * sg * sg;
    float sum = 0.0f;
    for (int j = 0; j < 64; ++j) {
      float d = (float)(i - j);
      sum += expf(-(d * d) / denom);
    }
    float inv = 1.0f / fmaxf(sum, 1e-12f);
    for (int j = 0; j < 64; ++j) {
      float d = (float)(i - j);
      base[KT_OFF + (li * 64 + i) * 64 + j] = (_Float16)(expf(-(d * d) / denom) * inv);
    }
  } else {
    // small layer weights, zero-padded to MFMA tiles
    for (int r = tid; r < 4608; r += 256) {
      float v;
      if (r < 1024)      { int o = r >> 6, c = r & 63;             v = (o < 8)  ? w0[o * 64 + c] : 0.0f; }
      else if (r < 1536) { int q = r - 1024; int o = q >> 5, c = q & 31; v = (c < 8)  ? w1[o * 8 + c]  : 0.0f; }
      else if (r < 2560) { int q = r - 1536; int o = q >> 5, c = q & 31; v = (c < 16) ? w2[o * 16 + c] : 0.0f; }
      else               { int q = r - 2560; int o = q >> 5, c = q & 31; v = w3[o * 32 + c]; }
      base[W0P_OFF + r] = (_Float16)v;
    }
  }
}

__device__ __forceinline__ float leaky(float v) { return v > 0.0f ? v : 0.01f * v; }

// swizzled offset (halves) in an 8KB 64x64 fp16 buffer: 16B chunk j -> j ^ (row&7) ^ sx
__device__ __forceinline__ int swz(int sx, int row, int c) {
  return row * 64 + ((((c >> 3) ^ (row & 7) ^ sx) & 7) << 3) + (c & 7);
}

// sched fence: DS reads/writes may not cross (in-place transpose WAR hazard);
// VALU/SALU/MFMA/VMEM free to pipeline across stages.
#define DS_FENCE() __builtin_amdgcn_sched_barrier(0x7F)

// stage A: xpT[o][h] from act_R[h][c] (LDS) and w[o][c] (ws).
template<int NT, int KC, int KPAD>
__device__ __forceinline__ void stage_a1(_Float16* P, int sx,
                                         const _Float16* wp, const float* bv,
                                         int lo, int hi) {
  DS_FENCE();        // prior stage's DS writes stay above
  f16x8 a[4][KC];
#pragma unroll
  for (int mt = 0; mt < 4; ++mt)
#pragma unroll
    for (int kc = 0; kc < KC; ++kc)
      a[mt][kc] = *(const f16x8*)(P + swz(sx, mt * 16 + lo, kc * 32 + hi * 8));
  f16x8 wf[NT][KC];
#pragma unroll
  for (int nt = 0; nt < NT; ++nt)
#pragma unroll
    for (int kc = 0; kc < KC; ++kc)
      wf[nt][kc] = *(const f16x8*)(wp + (nt * 16 + lo) * KPAD + kc * 32 + hi * 8);
  DS_FENCE();        // all DS reads above; all DS writes below
#pragma unroll
  for (int mt = 0; mt < 4; ++mt)
#pragma unroll
    for (int nt = 0; nt < NT; ++nt) {
      f32x4 acc = {0.0f, 0.0f, 0.0f, 0.0f};
#pragma unroll
      for (int kc = 0; kc < KC; ++kc)
        acc = __builtin_amdgcn_mfma_f32_16x16x32_f16(a[mt][kc], wf[nt][kc], acc, 0, 0, 0);
      f16x4 hv;
#pragma unroll
      for (int r = 0; r < 4; ++r) hv[r] = (_Float16)(acc[r] + bv[nt]);
      *(f16x4*)(P + swz(sx, nt * 16 + lo, mt * 16 + hi * 4)) = hv;
    }
}

// stage B: act_R[i][o] = leaky(sum_j K~[i][j] * xpT[o][j])
template<int MT>
__device__ __forceinline__ void stage_b1(_Float16* P, int sx,
                                         const _Float16* kmat, int lo, int hi) {
  DS_FENCE();
  f16x8 ax[MT][2];
#pragma unroll
  for (int ot = 0; ot < MT; ++ot)
#pragma unroll
    for (int kc = 0; kc < 2; ++kc)
      ax[ot][kc] = *(const f16x8*)(P + swz(sx, ot * 16 + lo, kc * 32 + hi * 8));
  f16x8 kb[4][2];
#pragma unroll
  for (int nt = 0; nt < 4; ++nt)
#pragma unroll
    for (int kc = 0; kc < 2; ++kc)
      kb[nt][kc] = *(const f16x8*)(kmat + (nt * 16 + lo) * 64 + kc * 32 + hi * 8);
  DS_FENCE();
#pragma unroll
  for (int ot = 0; ot < MT; ++ot)
#pragma unroll
    for (int nt = 0; nt < 4; ++nt) {
      f32x4 acc = {0.0f, 0.0f, 0.0f, 0.0f};
#pragma unroll
      for (int kc = 0; kc < 2; ++kc)
        acc = __builtin_amdgcn_mfma_f32_16x16x32_f16(ax[ot][kc], kb[nt][kc], acc, 0, 0, 0);
      f16x4 hv;
#pragma unroll
      for (int r = 0; r < 4; ++r) hv[r] = (_Float16)leaky(acc[r]);
      *(f16x4*)(P + swz(sx, nt * 16 + lo, ot * 16 + hi * 4)) = hv;
    }
}

__global__ __launch_bounds__(1024, 4)
void fused(const float* __restrict__ x,
           const float* __restrict__ bb0, const float* __restrict__ bb1,
           const float* __restrict__ bb2, const float* __restrict__ bb3,
           const _Float16* __restrict__ wsh,
           const float* __restrict__ bm0, const float* __restrict__ wm1,
           const float* __restrict__ bm1, float* __restrict__ out, int B) {
  __shared__ _Float16 lds[16][4096];  // 128KB: 16 samples x (64x64 fp16)
  const int tid = threadIdx.x;
  const int wv = tid >> 6, lane = tid & 63;
  const int lo = lane & 15, hi = lane >> 4;
  const int smp0 = blockIdx.x * 16;
  int smp = smp0 + wv;  if (smp >= B) smp = B - 1;   // clamp; masked at final store
  _Float16* P = lds[wv];
  const int sx = wv;                  // swz masks &7 internally

  // zero-init the wave's buffer: stale LDS can contain NaN bit patterns, and
  // NaN*0 = NaN through the zero-padded-weight MFMAs (R9 failure).
  {
    f16x8 z = {};
#pragma unroll
    for (int t = 0; t < 8; ++t)
      *(f16x8*)(P + t * 512 + lane * 8) = z;
  }

  float bv0 = (lo < 8) ? bb0[lo] : 0.0f;
  float bv1 = bb1[lo];
  float bv2[2] = {bb2[lo], bb2[16 + lo]};
  float bv3[4] = {bb3[lo], bb3[16 + lo], bb3[32 + lo], bb3[48 + lo]};

  // ---- layer 0: A-frags direct from global fp32 x (no LDS staging) ----
  const float* xr = x + (size_t)smp * 4096;
  f16x8 a0[4][2];
#pragma unroll
  for (int mt = 0; mt < 4; ++mt)
#pragma unroll
    for (int kc = 0; kc < 2; ++kc) {
      const float4* p4 = (const float4*)(xr + (mt * 16 + lo) * 64 + kc * 32 + hi * 8);
      float4 v0 = p4[0], v1 = p4[1];
      f16x8 a;
      a[0] = (_Float16)v0.x; a[1] = (_Float16)v0.y; a[2] = (_Float16)v0.z; a[3] = (_Float16)v0.w;
      a[4] = (_Float16)v1.x; a[5] = (_Float16)v1.y; a[6] = (_Float16)v1.z; a[7] = (_Float16)v1.w;
      a0[mt][kc] = a;
    }
  f16x8 wf0[2];
#pragma unroll
  for (int kc = 0; kc < 2; ++kc)
    wf0[kc] = *(const f16x8*)(wsh + W0P_OFF + lo * 64 + kc * 32 + hi * 8);
  DS_FENCE();          // zero-init above; layer-0 xpT writes below
#pragma unroll
  for (int mt = 0; mt < 4; ++mt) {
    f32x4 acc = {0.0f, 0.0f, 0.0f, 0.0f};
#pragma unroll
    for (int kc = 0; kc < 2; ++kc)
      acc = __builtin_amdgcn_mfma_f32_16x16x32_f16(a0[mt][kc], wf0[kc], acc, 0, 0, 0);
    f16x4 hv;
#pragma unroll
    for (int r = 0; r < 4; ++r) hv[r] = (_Float16)(acc[r] + bv0);
    *(f16x4*)(P + swz(sx, lo, mt * 16 + hi * 4)) = hv;     // nt = 0 only (8 feats)
  }

  const _Float16* kt = wsh + KT_OFF;
  stage_b1<1>(P, sx, kt + 0 * 4096, lo, hi);
  stage_a1<1, 1, 32>(P, sx, wsh + W1P_OFF, &bv1, lo, hi);
  stage_b1<1>(P, sx, kt + 1 * 4096, lo, hi);
  stage_a1<2, 1, 32>(P, sx, wsh + W2P_OFF, bv2, lo, hi);
  stage_b1<2>(P, sx, kt + 2 * 4096, lo, hi);
  stage_a1<4, 1, 32>(P, sx, wsh + W3P_OFF, bv3, lo, hi);
  stage_b1<4>(P, sx, kt + 3 * 4096, lo, hi);

  __syncthreads();   // all 16 sample buffers complete before cross-wave dense reads

  // ---- phase D0: out80 = wm0 @ h.  A rows = 16 samples, 16-way K split ----
  f32x4 acc[5];
#pragma unroll
  for (int nt = 0; nt < 5; ++nt) { f32x4 z = {0.0f, 0.0f, 0.0f, 0.0f}; acc[nt] = z; }

  const _Float16* ap = &lds[lo][0];
#pragma unroll 2
  for (int it = 0; it < 8; ++it) {
    int kc = wv * 8 + it;                  // 128 kc chunks of 32 halves
    int row = kc >> 1, cc = (kc & 1) * 32 + hi * 8;
    f16x8 a = *(const f16x8*)(ap + swz(lo, row, cc));
    const _Float16* bp = wsh + (size_t)kc * 2560 + lo * 32 + hi * 8;
#pragma unroll
    for (int nt = 0; nt < 5; ++nt) {
      f16x8 b = *(const f16x8*)(bp + nt * 512);
      acc[nt] = __builtin_amdgcn_mfma_f32_16x16x32_f16(a, b, acc[nt], 0, 0, 0);
    }
  }
  __syncthreads();                         // all dense reads of lds done

  // partials into reused LDS: part[wv][m<16][80]  (16 waves x 1280 floats = 80KB)
  float* scr = (float*)&lds[0][0];
#pragma unroll
  for (int nt = 0; nt < 5; ++nt)
#pragma unroll
    for (int r = 0; r < 4; ++r)
      scr[wv * 1280 + (hi * 4 + r) * 80 + nt * 16 + lo] = acc[nt][r];
  __syncthreads();

  // reduce across 16 waves + bias + leaky -> h1[16][80]
  float* h1 = scr + 20480;
  for (int e = tid; e < 1280; e += 1024) {
    int m = e / 80, n = e - m * 80;
    float v = bm0[n];
#pragma unroll
    for (int w = 0; w < 16; ++w) v += scr[w * 1280 + e];
    h1[e] = leaky(v);
  }
  __syncthreads();

  // ---- phase D1: out60 = wm1 @ h1 ----
  for (int e = tid; e < 960; e += 1024) {
    int m = e / 60, n = e - m * 60;
    float v = bm1[n];
    const float4* hr = (const float4*)(h1 + m * 80);
    const float4* wr = (const float4*)(wm1 + n * 80);
#pragma unroll
    for (int k2 = 0; k2 < 20; ++k2) {
      float4 hv = hr[k2], wv4 = wr[k2];
      v += hv.x * wv4.x + hv.y * wv4.y + hv.z * wv4.z + hv.w * wv4.w;
    }
    int s = smp0 + m;
    if (s < B) out[(size_t)s * 60 + n] = leaky(v);
  }
}

extern "C" void kernel_launch(void* const* d_in, const int* in_sizes, int n_in,
                              void* d_out, int out_size, void* d_ws, size_t ws_size,
                              hipStream_t stream) {
  const float* x   = (const float*)d_in[0];
  const float* w0  = (const float*)d_in[1];
  const float* b0  = (const float*)d_in[2];
  const float* s0  = (const float*)d_in[3];
  const float* w1  = (const float*)d_in[4];
  const float* b1  = (const float*)d_in[5];
  const float* s1  = (const float*)d_in[6];
  const float* w2  = (const float*)d_in[7];
  const float* b2  = (const float*)d_in[8];
  const float* s2  = (const float*)d_in[9];
  const float* w3  = (const float*)d_in[10];
  const float* b3  = (const float*)d_in[11];
  const float* s3  = (const float*)d_in[12];
  const float* wm0 = (const float*)d_in[13];
  const float* bm0 = (const float*)d_in[14];
  const float* wm1 = (const float*)d_in[15];
  const float* bm1 = (const float*)d_in[16];
  float* out = (float*)d_out;
  _Float16* wsh = (_Float16*)d_ws;

  int B = in_sizes[0] / 4096;

  prep_all<<<1282, 256, 0, stream>>>(s0, s1, s2, s3, w0, w1, w2, w3, wm0, wsh);
  fused<<<(B + 15) / 16, 1024, 0, stream>>>(x, b0, b1, b2, b3, wsh, bm0, wm1, bm1, out, B);
}

// Round 8
// 177.900 us; speedup vs baseline: 1.0087x; 1.0087x over previous
//
#include <hip/hip_runtime.h>

// R12 = R11 resubmitted verbatim (previous round failed on infra, not kernel).
// R11: R10 + depth-1 software pipeline of K~/weight fragments.
// Each gauss stage's global (L2) weight fragments are loaded into VGPRs one
// full stage EARLY, removing ~200-400cy L2 latency from every stage hop of
// the wave-private chain. Stage bodies take preloaded frags; DS fences (0x7F,
// DS-only) unchanged; structure otherwise identical to R10:
// 16 waves/block, one chain per sample, 16 samples in 128KB LDS, fused dense.

typedef _Float16 f16x8 __attribute__((ext_vector_type(8)));
typedef _Float16 f16x4 __attribute__((ext_vector_type(4)));
typedef float    f32x4 __attribute__((ext_vector_type(4)));

// ws layout (halves): [0] wm0 tiled [128][80][32]; K~ [4][64][64]; padded weights
#define KT_OFF    327680
#define W0P_OFF   344064               // [16][64], rows>=8 zero
#define W1P_OFF   345088               // [16][32], cols>=8 zero
#define W2P_OFF   345600               // [32][32], cols>=16 zero
#define W3P_OFF   346624               // [64][32]

__global__ void prep_all(const float* __restrict__ s0, const float* __restrict__ s1,
                         const float* __restrict__ s2, const float* __restrict__ s3,
                         const float* __restrict__ w0, const float* __restrict__ w1,
                         const float* __restrict__ w2, const float* __restrict__ w3,
                         const float* __restrict__ wm0, _Float16* __restrict__ base) {
  int bid = blockIdx.x, tid = threadIdx.x;
  if (bid < 1280) {
    // wm0 fp32 [80][4096] -> fp16 tiled [kc][n][32]
    int idx = bid * 256 + tid;
    int kc = idx / 2560, rem = idx % 2560;
    int n = rem >> 5, o = rem & 31;
    base[idx] = (_Float16)wm0[n * 4096 + kc * 32 + o];
  } else if (bid == 1280) {
    // K~ : L1-normalized gaussian rows, fp16 [4][64][64]
    int li = tid >> 6, i = tid & 63;
    float sg = (li == 0) ? s0[0] : (li == 1) ? s1[0] : (li == 2) ? s2[0] : s3[0];
    float denom = 2.0f * sg * sg;
    float sum = 0.0f;
    for (int j = 0; j < 64; ++j) {
      float d = (float)(i - j);
      sum += expf(-(d * d) / denom);
    }
    float inv = 1.0f / fmaxf(sum, 1e-12f);
    for (int j = 0; j < 64; ++j) {
      float d = (float)(i - j);
      base[KT_OFF + (li * 64 + i) * 64 + j] = (_Float16)(expf(-(d * d) / denom) * inv);
    }
  } else {
    // small layer weights, zero-padded to MFMA tiles
    for (int r = tid; r < 4608; r += 256) {
      float v;
      if (r < 1024)      { int o = r >> 6, c = r & 63;             v = (o < 8)  ? w0[o * 64 + c] : 0.0f; }
      else if (r < 1536) { int q = r - 1024; int o = q >> 5, c = q & 31; v = (c < 8)  ? w1[o * 8 + c]  : 0.0f; }
      else if (r < 2560) { int q = r - 1536; int o = q >> 5, c = q & 31; v = (c < 16) ? w2[o * 16 + c] : 0.0f; }
      else               { int q = r - 2560; int o = q >> 5, c = q & 31; v = w3[o * 32 + c]; }
      base[W0P_OFF + r] = (_Float16)v;
    }
  }
}

__device__ __forceinline__ float leaky(float v) { return v > 0.0f ? v : 0.01f * v; }

// swizzled offset (halves) in an 8KB 64x64 fp16 buffer: 16B chunk j -> j ^ (row&7) ^ sx
__device__ __forceinline__ int swz(int sx, int row, int c) {
  return row * 64 + ((((c >> 3) ^ (row & 7) ^ sx) & 7) << 3) + (c & 7);
}

// sched fence: DS reads/writes may not cross (in-place transpose WAR hazard);
// VALU/SALU/MFMA/VMEM free to pipeline across stages (incl. weight prefetch).
#define DS_FENCE() __builtin_amdgcn_sched_barrier(0x7F)

__device__ __forceinline__ f16x8 ldf(const _Float16* p) { return *(const f16x8*)p; }

// stage A with PRELOADED weight frags wf[NT*KC]: xpT[o][h] from act_R[h][c].
template<int NT, int KC>
__device__ __forceinline__ void stage_a_pre(_Float16* P, int sx,
                                            const f16x8* wf, const float* bv,
                                            int lo, int hi) {
  DS_FENCE();        // prior stage's DS writes stay above
  f16x8 a[4][KC];
#pragma unroll
  for (int mt = 0; mt < 4; ++mt)
#pragma unroll
    for (int kc = 0; kc < KC; ++kc)
      a[mt][kc] = ldf(P + swz(sx, mt * 16 + lo, kc * 32 + hi * 8));
  DS_FENCE();        // all DS reads above; all DS writes below
#pragma unroll
  for (int mt = 0; mt < 4; ++mt)
#pragma unroll
    for (int nt = 0; nt < NT; ++nt) {
      f32x4 acc = {0.0f, 0.0f, 0.0f, 0.0f};
#pragma unroll
      for (int kc = 0; kc < KC; ++kc)
        acc = __builtin_amdgcn_mfma_f32_16x16x32_f16(a[mt][kc], wf[nt * KC + kc], acc, 0, 0, 0);
      f16x4 hv;
#pragma unroll
      for (int r = 0; r < 4; ++r) hv[r] = (_Float16)(acc[r] + bv[nt]);
      *(f16x4*)(P + swz(sx, nt * 16 + lo, mt * 16 + hi * 4)) = hv;
    }
}

// stage B with PRELOADED kb[8] (= kb[nt][kc]): act_R[i][o] = leaky(K~ @ xpT^T)
template<int MT>
__device__ __forceinline__ void stage_b_pre(_Float16* P, int sx,
                                            const f16x8* kb, int lo, int hi) {
  DS_FENCE();
  f16x8 ax[MT][2];
#pragma unroll
  for (int ot = 0; ot < MT; ++ot)
#pragma unroll
    for (int kc = 0; kc < 2; ++kc)
      ax[ot][kc] = ldf(P + swz(sx, ot * 16 + lo, kc * 32 + hi * 8));
  DS_FENCE();
#pragma unroll
  for (int ot = 0; ot < MT; ++ot)
#pragma unroll
    for (int nt = 0; nt < 4; ++nt) {
      f32x4 acc = {0.0f, 0.0f, 0.0f, 0.0f};
#pragma unroll
      for (int kc = 0; kc < 2; ++kc)
        acc = __builtin_amdgcn_mfma_f32_16x16x32_f16(ax[ot][kc], kb[nt * 2 + kc], acc, 0, 0, 0);
      f16x4 hv;
#pragma unroll
      for (int r = 0; r < 4; ++r) hv[r] = (_Float16)leaky(acc[r]);
      *(f16x4*)(P + swz(sx, nt * 16 + lo, ot * 16 + hi * 4)) = hv;
    }
}

__global__ __launch_bounds__(1024, 4)
void fused(const float* __restrict__ x,
           const float* __restrict__ bb0, const float* __restrict__ bb1,
           const float* __restrict__ bb2, const float* __restrict__ bb3,
           const _Float16* __restrict__ wsh,
           const float* __restrict__ bm0, const float* __restrict__ wm1,
           const float* __restrict__ bm1, float* __restrict__ out, int B) {
  __shared__ _Float16 lds[16][4096];  // 128KB: 16 samples x (64x64 fp16)
  const int tid = threadIdx.x;
  const int wv = tid >> 6, lane = tid & 63;
  const int lo = lane & 15, hi = lane >> 4;
  const int smp0 = blockIdx.x * 16;
  int smp = smp0 + wv;  if (smp >= B) smp = B - 1;   // clamp; masked at final store
  _Float16* P = lds[wv];
  const int sx = wv;                  // swz masks &7 internally
  const _Float16* kt = wsh + KT_OFF;

  // zero-init the wave's buffer: stale LDS can contain NaN bit patterns, and
  // NaN*0 = NaN through the zero-padded-weight MFMAs (R9 failure).
  {
    f16x8 z = {};
#pragma unroll
    for (int t = 0; t < 8; ++t)
      *(f16x8*)(P + t * 512 + lane * 8) = z;
  }

  float bv0 = (lo < 8) ? bb0[lo] : 0.0f;
  float bv1 = bb1[lo];
  float bv2[2] = {bb2[lo], bb2[16 + lo]};
  float bv3[4] = {bb3[lo], bb3[16 + lo], bb3[32 + lo], bb3[48 + lo]};

  // ---- prefetch S0 (L0 weights) + S1 (kt0) fragments ----
  f16x8 wf0[2];
#pragma unroll
  for (int kc = 0; kc < 2; ++kc)
    wf0[kc] = ldf(wsh + W0P_OFF + lo * 64 + kc * 32 + hi * 8);
  f16x8 kbA[8];
#pragma unroll
  for (int nt = 0; nt < 4; ++nt)
#pragma unroll
    for (int kc = 0; kc < 2; ++kc)
      kbA[nt * 2 + kc] = ldf(kt + 0 * 4096 + (nt * 16 + lo) * 64 + kc * 32 + hi * 8);

  // ---- S0: layer-0 A direct from global fp32 x (no LDS staging) ----
  const float* xr = x + (size_t)smp * 4096;
  f16x8 a0[4][2];
#pragma unroll
  for (int mt = 0; mt < 4; ++mt)
#pragma unroll
    for (int kc = 0; kc < 2; ++kc) {
      const float4* p4 = (const float4*)(xr + (mt * 16 + lo) * 64 + kc * 32 + hi * 8);
      float4 v0 = p4[0], v1 = p4[1];
      f16x8 a;
      a[0] = (_Float16)v0.x; a[1] = (_Float16)v0.y; a[2] = (_Float16)v0.z; a[3] = (_Float16)v0.w;
      a[4] = (_Float16)v1.x; a[5] = (_Float16)v1.y; a[6] = (_Float16)v1.z; a[7] = (_Float16)v1.w;
      a0[mt][kc] = a;
    }
  DS_FENCE();          // zero-init above; layer-0 xpT writes below
#pragma unroll
  for (int mt = 0; mt < 4; ++mt) {
    f32x4 acc = {0.0f, 0.0f, 0.0f, 0.0f};
#pragma unroll
    for (int kc = 0; kc < 2; ++kc)
      acc = __builtin_amdgcn_mfma_f32_16x16x32_f16(a0[mt][kc], wf0[kc], acc, 0, 0, 0);
    f16x4 hv;
#pragma unroll
    for (int r = 0; r < 4; ++r) hv[r] = (_Float16)(acc[r] + bv0);
    *(f16x4*)(P + swz(sx, lo, mt * 16 + hi * 4)) = hv;     // nt = 0 only (8 feats)
  }

  // ---- pipelined chain: load stage i+1 frags, run stage i ----
  f16x8 wfA1[1];
  wfA1[0] = ldf(wsh + W1P_OFF + lo * 32 + hi * 8);                     // S2 frags
  stage_b_pre<1>(P, sx, kbA, lo, hi);                                  // S1 (kt0)

  f16x8 kbB[8];
#pragma unroll
  for (int nt = 0; nt < 4; ++nt)
#pragma unroll
    for (int kc = 0; kc < 2; ++kc)
      kbB[nt * 2 + kc] = ldf(kt + 1 * 4096 + (nt * 16 + lo) * 64 + kc * 32 + hi * 8);
  stage_a_pre<1, 1>(P, sx, wfA1, &bv1, lo, hi);                        // S2 (w1)

  f16x8 wfA2[2];
#pragma unroll
  for (int nt = 0; nt < 2; ++nt)
    wfA2[nt] = ldf(wsh + W2P_OFF + (nt * 16 + lo) * 32 + hi * 8);      // S4 frags
  stage_b_pre<1>(P, sx, kbB, lo, hi);                                  // S3 (kt1)

  f16x8 kbC[8];
#pragma unroll
  for (int nt = 0; nt < 4; ++nt)
#pragma unroll
    for (int kc = 0; kc < 2; ++kc)
      kbC[nt * 2 + kc] = ldf(kt + 2 * 4096 + (nt * 16 + lo) * 64 + kc * 32 + hi * 8);
  stage_a_pre<2, 1>(P, sx, wfA2, bv2, lo, hi);                         // S4 (w2)

  f16x8 wfA3[4];
#pragma unroll
  for (int nt = 0; nt < 4; ++nt)
    wfA3[nt] = ldf(wsh + W3P_OFF + (nt * 16 + lo) * 32 + hi * 8);      // S6 frags
  stage_b_pre<2>(P, sx, kbC, lo, hi);                                  // S5 (kt2)

  f16x8 kbD[8];
#pragma unroll
  for (int nt = 0; nt < 4; ++nt)
#pragma unroll
    for (int kc = 0; kc < 2; ++kc)
      kbD[nt * 2 + kc] = ldf(kt + 3 * 4096 + (nt * 16 + lo) * 64 + kc * 32 + hi * 8);
  stage_a_pre<4, 1>(P, sx, wfA3, bv3, lo, hi);                         // S6 (w3)

  stage_b_pre<4>(P, sx, kbD, lo, hi);                                  // S7 (kt3)

  __syncthreads();   // all 16 sample buffers complete before cross-wave dense reads

  // ---- phase D0: out80 = wm0 @ h.  A rows = 16 samples, 16-way K split ----
  f32x4 acc[5];
#pragma unroll
  for (int nt = 0; nt < 5; ++nt) { f32x4 z = {0.0f, 0.0f, 0.0f, 0.0f}; acc[nt] = z; }

  const _Float16* ap = &lds[lo][0];
#pragma unroll 2
  for (int it = 0; it < 8; ++it) {
    int kc = wv * 8 + it;                  // 128 kc chunks of 32 halves
    int row = kc >> 1, cc = (kc & 1) * 32 + hi * 8;
    f16x8 a = *(const f16x8*)(ap + swz(lo, row, cc));
    const _Float16* bp = wsh + (size_t)kc * 2560 + lo * 32 + hi * 8;
#pragma unroll
    for (int nt = 0; nt < 5; ++nt) {
      f16x8 b = *(const f16x8*)(bp + nt * 512);
      acc[nt] = __builtin_amdgcn_mfma_f32_16x16x32_f16(a, b, acc[nt], 0, 0, 0);
    }
  }
  __syncthreads();                         // all dense reads of lds done

  // partials into reused LDS: part[wv][m<16][80]  (16 waves x 1280 floats = 80KB)
  float* scr = (float*)&lds[0][0];
#pragma unroll
  for (int nt = 0; nt < 5; ++nt)
#pragma unroll
    for (int r = 0; r < 4; ++r)
      scr[wv * 1280 + (hi * 4 + r) * 80 + nt * 16 + lo] = acc[nt][r];
  __syncthreads();

  // reduce across 16 waves + bias + leaky -> h1[16][80]
  float* h1 = scr + 20480;
  for (int e = tid; e < 1280; e += 1024) {
    int m = e / 80, n = e - m * 80;
    float v = bm0[n];
#pragma unroll
    for (int w = 0; w < 16; ++w) v += scr[w * 1280 + e];
    h1[e] = leaky(v);
  }
  __syncthreads();

  // ---- phase D1: out60 = wm1 @ h1 ----
  for (int e = tid; e < 960; e += 1024) {
    int m = e / 60, n = e - m * 60;
    float v = bm1[n];
    const float4* hr = (const float4*)(h1 + m * 80);
    const float4* wr = (const float4*)(wm1 + n * 80);
#pragma unroll
    for (int k2 = 0; k2 < 20; ++k2) {
      float4 hv = hr[k2], wv4 = wr[k2];
      v += hv.x * wv4.x + hv.y * wv4.y + hv.z * wv4.z + hv.w * wv4.w;
    }
    int s = smp0 + m;
    if (s < B) out[(size_t)s * 60 + n] = leaky(v);
  }
}

extern "C" void kernel_launch(void* const* d_in, const int* in_sizes, int n_in,
                              void* d_out, int out_size, void* d_ws, size_t ws_size,
                              hipStream_t stream) {
  const float* x   = (const float*)d_in[0];
  const float* w0  = (const float*)d_in[1];
  const float* b0  = (const float*)d_in[2];
  const float* s0  = (const float*)d_in[3];
  const float* w1  = (const float*)d_in[4];
  const float* b1  = (const float*)d_in[5];
  const float* s1  = (const float*)d_in[6];
  const float* w2  = (const float*)d_in[7];
  const float* b2  = (const float*)d_in[8];
  const float* s2  = (const float*)d_in[9];
  const float* w3  = (const float*)d_in[10];
  const float* b3  = (const float*)d_in[11];
  const float* s3  = (const float*)d_in[12];
  const float* wm0 = (const float*)d_in[13];
  const float* bm0 = (const float*)d_in[14];
  const float* wm1 = (const float*)d_in[15];
  const float* bm1 = (const float*)d_in[16];
  float* out = (float*)d_out;
  _Float16* wsh = (_Float16*)d_ws;

  int B = in_sizes[0] / 4096;

  prep_all<<<1282, 256, 0, stream>>>(s0, s1, s2, s3, w0, w1, w2, w3, wm0, wsh);
  fused<<<(B + 15) / 16, 1024, 0, stream>>>(x, b0, b1, b2, b3, wsh, bm0, wm1, bm1, out, B);
}

// Round 10
// 176.039 us; speedup vs baseline: 1.0194x; 1.0106x over previous
//
#include <hip/hip_runtime.h>

// R14 = R13 with the cvt_pkrtz type fix (builtin returns __fp16x2; use a
// __fp16-typed union member — identical bits, no codegen change).
// R13: issue-count surgery on the two critical pipes:
// - bias folded into MFMA C-operand (acc init = bias)
// - v_cvt_pkrtz packed f32->f16 epilogues & x-ingest
// - S2/S4 use mfma_f32_16x16x16f16 (K=16): no K-pad stale reads, b64 frags
// - zero-init DELETED (every chain read is write-before-read with K=16 S2/S4)
// Structure: 16 waves/block, one wave-private chain per sample, 16 samples in
// 128KB LDS, depth-1 weight prefetch, fused 16-sample dense + reduce + D1.

typedef _Float16 f16x8 __attribute__((ext_vector_type(8)));
typedef _Float16 f16x4 __attribute__((ext_vector_type(4)));
typedef __fp16   hf2   __attribute__((ext_vector_type(2)));   // cvt_pkrtz result type
typedef float    f32x4 __attribute__((ext_vector_type(4)));

// ws layout (halves): wm0 tiled [128][80][32]; K~ [4][64][64]; padded weights
#define KT_OFF    327680
#define W0P_OFF   344064               // [16][64], rows>=8 zero
#define W1P_OFF   345088               // [16][16], cols>=8 zero
#define W2P_OFF   345344               // [32][16], all valid
#define W3P_OFF   345856               // [64][32]

__global__ void prep_all(const float* __restrict__ s0, const float* __restrict__ s1,
                         const float* __restrict__ s2, const float* __restrict__ s3,
                         const float* __restrict__ w0, const float* __restrict__ w1,
                         const float* __restrict__ w2, const float* __restrict__ w3,
                         const float* __restrict__ wm0, _Float16* __restrict__ base) {
  int bid = blockIdx.x, tid = threadIdx.x;
  if (bid < 1280) {
    // wm0 fp32 [80][4096] -> fp16 tiled [kc][n][32]
    int idx = bid * 256 + tid;
    int kc = idx / 2560, rem = idx % 2560;
    int n = rem >> 5, o = rem & 31;
    base[idx] = (_Float16)wm0[n * 4096 + kc * 32 + o];
  } else if (bid == 1280) {
    // K~ : L1-normalized gaussian rows, fp16 [4][64][64]
    int li = tid >> 6, i = tid & 63;
    float sg = (li == 0) ? s0[0] : (li == 1) ? s1[0] : (li == 2) ? s2[0] : s3[0];
    float denom = 2.0f * sg * sg;
    float sum = 0.0f;
    for (int j = 0; j < 64; ++j) {
      float d = (float)(i - j);
      sum += expf(-(d * d) / denom);
    }
    float inv = 1.0f / fmaxf(sum, 1e-12f);
    for (int j = 0; j < 64; ++j) {
      float d = (float)(i - j);
      base[KT_OFF + (li * 64 + i) * 64 + j] = (_Float16)(expf(-(d * d) / denom) * inv);
    }
  } else {
    // small layer weights, zero-padded to MFMA tiles (3840 halves total)
    for (int r = tid; r < 3840; r += 256) {
      float v;
      if (r < 1024)      { int o = r >> 6, c = r & 63;             v = (o < 8) ? w0[o * 64 + c] : 0.0f; }
      else if (r < 1280) { int q = r - 1024; int o = q >> 4, c = q & 15; v = (c < 8) ? w1[o * 8 + c] : 0.0f; }
      else if (r < 1792) { int q = r - 1280; int o = q >> 4, c = q & 15; v = w2[o * 16 + c]; }
      else               { int q = r - 1792; int o = q >> 5, c = q & 31; v = w3[o * 32 + c]; }
      base[W0P_OFF + r] = (_Float16)v;
    }
  }
}

__device__ __forceinline__ float leaky(float v) { return v > 0.0f ? v : 0.01f * v; }

// packed f32x4 -> f16x4 via v_cvt_pkrtz (2 instrs instead of 4 cvt + 2 pack)
__device__ __forceinline__ f16x4 pk4(float a, float b, float c, float d) {
  union { f16x4 v; hf2 p[2]; } u;
  u.p[0] = __builtin_amdgcn_cvt_pkrtz(a, b);
  u.p[1] = __builtin_amdgcn_cvt_pkrtz(c, d);
  return u.v;
}

// swizzled offset (halves) in an 8KB 64x64 fp16 buffer: 16B chunk j -> j ^ (row&7) ^ sx
__device__ __forceinline__ int swz(int sx, int row, int c) {
  return row * 64 + ((((c >> 3) ^ (row & 7) ^ sx) & 7) << 3) + (c & 7);
}

// sched fence: DS reads/writes may not cross (in-place transpose WAR hazard);
// VALU/SALU/MFMA/VMEM free to pipeline across stages (incl. weight prefetch).
#define DS_FENCE() __builtin_amdgcn_sched_barrier(0x7F)

__device__ __forceinline__ f16x8 ldf(const _Float16* p) { return *(const f16x8*)p; }
__device__ __forceinline__ f16x4 ldf4(const _Float16* p) { return *(const f16x4*)p; }

// stage A, K=32 chunks (b128 frags), PRELOADED weights, bias in C-operand.
template<int NT, int KC>
__device__ __forceinline__ void stage_a_pre(_Float16* P, int sx,
                                            const f16x8* wf, const float* bv,
                                            int lo, int hi) {
  DS_FENCE();        // prior stage's DS writes stay above
  f16x8 a[4][KC];
#pragma unroll
  for (int mt = 0; mt < 4; ++mt)
#pragma unroll
    for (int kc = 0; kc < KC; ++kc)
      a[mt][kc] = ldf(P + swz(sx, mt * 16 + lo, kc * 32 + hi * 8));
  DS_FENCE();        // all DS reads above; all DS writes below
#pragma unroll
  for (int mt = 0; mt < 4; ++mt)
#pragma unroll
    for (int nt = 0; nt < NT; ++nt) {
      f32x4 acc = {bv[nt], bv[nt], bv[nt], bv[nt]};
#pragma unroll
      for (int kc = 0; kc < KC; ++kc)
        acc = __builtin_amdgcn_mfma_f32_16x16x32_f16(a[mt][kc], wf[nt * KC + kc], acc, 0, 0, 0);
      *(f16x4*)(P + swz(sx, nt * 16 + lo, mt * 16 + hi * 4)) =
          pk4(acc[0], acc[1], acc[2], acc[3]);
    }
}

// stage A, K=16 (b64 frags, mfma_16x16x16f16) for C_in<=16 layers: reads only
// the 16 valid cols -> no stale-region reads, narrower LDS ops.
template<int NT>
__device__ __forceinline__ void stage_a16_pre(_Float16* P, int sx,
                                              const f16x4* wf, const float* bv,
                                              int lo, int hi) {
  DS_FENCE();
  f16x4 a[4];
#pragma unroll
  for (int mt = 0; mt < 4; ++mt)
    a[mt] = ldf4(P + swz(sx, mt * 16 + lo, hi * 4));
  DS_FENCE();
#pragma unroll
  for (int mt = 0; mt < 4; ++mt)
#pragma unroll
    for (int nt = 0; nt < NT; ++nt) {
      f32x4 acc = {bv[nt], bv[nt], bv[nt], bv[nt]};
      acc = __builtin_amdgcn_mfma_f32_16x16x16f16(a[mt], wf[nt], acc, 0, 0, 0);
      *(f16x4*)(P + swz(sx, nt * 16 + lo, mt * 16 + hi * 4)) =
          pk4(acc[0], acc[1], acc[2], acc[3]);
    }
}

// stage B with PRELOADED kb[8]: act_R[i][o] = leaky(K~ @ xpT^T)
template<int MT>
__device__ __forceinline__ void stage_b_pre(_Float16* P, int sx,
                                            const f16x8* kb, int lo, int hi) {
  DS_FENCE();
  f16x8 ax[MT][2];
#pragma unroll
  for (int ot = 0; ot < MT; ++ot)
#pragma unroll
    for (int kc = 0; kc < 2; ++kc)
      ax[ot][kc] = ldf(P + swz(sx, ot * 16 + lo, kc * 32 + hi * 8));
  DS_FENCE();
#pragma unroll
  for (int ot = 0; ot < MT; ++ot)
#pragma unroll
    for (int nt = 0; nt < 4; ++nt) {
      f32x4 acc = {0.0f, 0.0f, 0.0f, 0.0f};
#pragma unroll
      for (int kc = 0; kc < 2; ++kc)
        acc = __builtin_amdgcn_mfma_f32_16x16x32_f16(ax[ot][kc], kb[nt * 2 + kc], acc, 0, 0, 0);
      *(f16x4*)(P + swz(sx, nt * 16 + lo, ot * 16 + hi * 4)) =
          pk4(leaky(acc[0]), leaky(acc[1]), leaky(acc[2]), leaky(acc[3]));
    }
}

__global__ __launch_bounds__(1024, 4)
void fused(const float* __restrict__ x,
           const float* __restrict__ bb0, const float* __restrict__ bb1,
           const float* __restrict__ bb2, const float* __restrict__ bb3,
           const _Float16* __restrict__ wsh,
           const float* __restrict__ bm0, const float* __restrict__ wm1,
           const float* __restrict__ bm1, float* __restrict__ out, int B) {
  __shared__ _Float16 lds[16][4096];  // 128KB: 16 samples x (64x64 fp16)
  const int tid = threadIdx.x;
  const int wv = tid >> 6, lane = tid & 63;
  const int lo = lane & 15, hi = lane >> 4;
  const int smp0 = blockIdx.x * 16;
  int smp = smp0 + wv;  if (smp >= B) smp = B - 1;   // clamp; masked at final store
  _Float16* P = lds[wv];
  const int sx = wv;                  // swz masks &7 internally
  const _Float16* kt = wsh + KT_OFF;

  float bv0 = (lo < 8) ? bb0[lo] : 0.0f;
  float bv1 = bb1[lo];
  float bv2[2] = {bb2[lo], bb2[16 + lo]};
  float bv3[4] = {bb3[lo], bb3[16 + lo], bb3[32 + lo], bb3[48 + lo]};

  // ---- prefetch S0 (L0 weights) + S1 (kt0) fragments ----
  f16x8 wf0[2];
#pragma unroll
  for (int kc = 0; kc < 2; ++kc)
    wf0[kc] = ldf(wsh + W0P_OFF + lo * 64 + kc * 32 + hi * 8);
  f16x8 kbA[8];
#pragma unroll
  for (int nt = 0; nt < 4; ++nt)
#pragma unroll
    for (int kc = 0; kc < 2; ++kc)
      kbA[nt * 2 + kc] = ldf(kt + 0 * 4096 + (nt * 16 + lo) * 64 + kc * 32 + hi * 8);

  // ---- S0: layer-0 A direct from global fp32 x (no LDS staging) ----
  const float* xr = x + (size_t)smp * 4096;
  f16x8 a0[4][2];
#pragma unroll
  for (int mt = 0; mt < 4; ++mt)
#pragma unroll
    for (int kc = 0; kc < 2; ++kc) {
      const float4* p4 = (const float4*)(xr + (mt * 16 + lo) * 64 + kc * 32 + hi * 8);
      float4 v0 = p4[0], v1 = p4[1];
      union { f16x8 v; hf2 p[4]; } u;
      u.p[0] = __builtin_amdgcn_cvt_pkrtz(v0.x, v0.y);
      u.p[1] = __builtin_amdgcn_cvt_pkrtz(v0.z, v0.w);
      u.p[2] = __builtin_amdgcn_cvt_pkrtz(v1.x, v1.y);
      u.p[3] = __builtin_amdgcn_cvt_pkrtz(v1.z, v1.w);
      a0[mt][kc] = u.v;
    }
  DS_FENCE();          // S0 xpT writes are the first DS ops on this buffer
#pragma unroll
  for (int mt = 0; mt < 4; ++mt) {
    f32x4 acc = {bv0, bv0, bv0, bv0};
#pragma unroll
    for (int kc = 0; kc < 2; ++kc)
      acc = __builtin_amdgcn_mfma_f32_16x16x32_f16(a0[mt][kc], wf0[kc], acc, 0, 0, 0);
    *(f16x4*)(P + swz(sx, lo, mt * 16 + hi * 4)) =
        pk4(acc[0], acc[1], acc[2], acc[3]);       // nt = 0 only (8 feats)
  }

  // ---- pipelined chain: load stage i+1 frags, run stage i ----
  f16x4 wfA1[1];
  wfA1[0] = ldf4(wsh + W1P_OFF + lo * 16 + hi * 4);                    // S2 frags
  stage_b_pre<1>(P, sx, kbA, lo, hi);                                  // S1 (kt0)

  f16x8 kbB[8];
#pragma unroll
  for (int nt = 0; nt < 4; ++nt)
#pragma unroll
    for (int kc = 0; kc < 2; ++kc)
      kbB[nt * 2 + kc] = ldf(kt + 1 * 4096 + (nt * 16 + lo) * 64 + kc * 32 + hi * 8);
  stage_a16_pre<1>(P, sx, wfA1, &bv1, lo, hi);                         // S2 (w1)

  f16x4 wfA2[2];
#pragma unroll
  for (int nt = 0; nt < 2; ++nt)
    wfA2[nt] = ldf4(wsh + W2P_OFF + (nt * 16 + lo) * 16 + hi * 4);     // S4 frags
  stage_b_pre<1>(P, sx, kbB, lo, hi);                                  // S3 (kt1)

  f16x8 kbC[8];
#pragma unroll
  for (int nt = 0; nt < 4; ++nt)
#pragma unroll
    for (int kc = 0; kc < 2; ++kc)
      kbC[nt * 2 + kc] = ldf(kt + 2 * 4096 + (nt * 16 + lo) * 64 + kc * 32 + hi * 8);
  stage_a16_pre<2>(P, sx, wfA2, bv2, lo, hi);                          // S4 (w2)

  f16x8 wfA3[4];
#pragma unroll
  for (int nt = 0; nt < 4; ++nt)
    wfA3[nt] = ldf(wsh + W3P_OFF + (nt * 16 + lo) * 32 + hi * 8);      // S6 frags
  stage_b_pre<2>(P, sx, kbC, lo, hi);                                  // S5 (kt2)

  f16x8 kbD[8];
#pragma unroll
  for (int nt = 0; nt < 4; ++nt)
#pragma unroll
    for (int kc = 0; kc < 2; ++kc)
      kbD[nt * 2 + kc] = ldf(kt + 3 * 4096 + (nt * 16 + lo) * 64 + kc * 32 + hi * 8);
  stage_a_pre<4, 1>(P, sx, wfA3, bv3, lo, hi);                         // S6 (w3)

  stage_b_pre<4>(P, sx, kbD, lo, hi);                                  // S7 (kt3)

  __syncthreads();   // all 16 sample buffers complete before cross-wave dense reads

  // ---- phase D0: out80 = wm0 @ h.  A rows = 16 samples, 16-way K split ----
  f32x4 acc[5];
#pragma unroll
  for (int nt = 0; nt < 5; ++nt) { f32x4 z = {0.0f, 0.0f, 0.0f, 0.0f}; acc[nt] = z; }

  const _Float16* ap = &lds[lo][0];
#pragma unroll 2
  for (int it = 0; it < 8; ++it) {
    int kc = wv * 8 + it;                  // 128 kc chunks of 32 halves
    int row = kc >> 1, cc = (kc & 1) * 32 + hi * 8;
    f16x8 a = *(const f16x8*)(ap + swz(lo, row, cc));
    const _Float16* bp = wsh + (size_t)kc * 2560 + lo * 32 + hi * 8;
#pragma unroll
    for (int nt = 0; nt < 5; ++nt) {
      f16x8 b = *(const f16x8*)(bp + nt * 512);
      acc[nt] = __builtin_amdgcn_mfma_f32_16x16x32_f16(a, b, acc[nt], 0, 0, 0);
    }
  }
  __syncthreads();                         // all dense reads of lds done

  // partials into reused LDS: part[wv][m<16][80]  (16 waves x 1280 floats = 80KB)
  float* scr = (float*)&lds[0][0];
#pragma unroll
  for (int nt = 0; nt < 5; ++nt)
#pragma unroll
    for (int r = 0; r < 4; ++r)
      scr[wv * 1280 + (hi * 4 + r) * 80 + nt * 16 + lo] = acc[nt][r];
  __syncthreads();

  // reduce across 16 waves + bias + leaky -> h1[16][80]
  float* h1 = scr + 20480;
  for (int e = tid; e < 1280; e += 1024) {
    int m = e / 80, n = e - m * 80;
    float v = bm0[n];
#pragma unroll
    for (int w = 0; w < 16; ++w) v += scr[w * 1280 + e];
    h1[e] = leaky(v);
  }
  __syncthreads();

  // ---- phase D1: out60 = wm1 @ h1 ----
  for (int e = tid; e < 960; e += 1024) {
    int m = e / 60, n = e - m * 60;
    float v = bm1[n];
    const float4* hr = (const float4*)(h1 + m * 80);
    const float4* wr = (const float4*)(wm1 + n * 80);
#pragma unroll
    for (int k2 = 0; k2 < 20; ++k2) {
      float4 hv = hr[k2], wv4 = wr[k2];
      v += hv.x * wv4.x + hv.y * wv4.y + hv.z * wv4.z + hv.w * wv4.w;
    }
    int s = smp0 + m;
    if (s < B) out[(size_t)s * 60 + n] = leaky(v);
  }
}

extern "C" void kernel_launch(void* const* d_in, const int* in_sizes, int n_in,
                              void* d_out, int out_size, void* d_ws, size_t ws_size,
                              hipStream_t stream) {
  const float* x   = (const float*)d_in[0];
  const float* w0  = (const float*)d_in[1];
  const float* b0  = (const float*)d_in[2];
  const float* s0  = (const float*)d_in[3];
  const float* w1  = (const float*)d_in[4];
  const float* b1  = (const float*)d_in[5];
  const float* s1  = (const float*)d_in[6];
  const float* w2  = (const float*)d_in[7];
  const float* b2  = (const float*)d_in[8];
  const float* s2  = (const float*)d_in[9];
  const float* w3  = (const float*)d_in[10];
  const float* b3  = (const float*)d_in[11];
  const float* s3  = (const float*)d_in[12];
  const float* wm0 = (const float*)d_in[13];
  const float* bm0 = (const float*)d_in[14];
  const float* wm1 = (const float*)d_in[15];
  const float* bm1 = (const float*)d_in[16];
  float* out = (float*)d_out;
  _Float16* wsh = (_Float16*)d_ws;

  int B = in_sizes[0] / 4096;

  prep_all<<<1282, 256, 0, stream>>>(s0, s1, s2, s3, w0, w1, w2, w3, wm0, wsh);
  fused<<<(B + 15) / 16, 1024, 0, stream>>>(x, b0, b1, b2, b3, wsh, bm0, wm1, bm1, out, B);
}